// Round 7
// baseline (242.541 us; speedup 1.0000x reference)
//
#include <hip/hip_runtime.h>
#include <hip/hip_fp16.h>

#define F0 18
#define F1 64
#define F2 32
#define BSHIFT 8            // bucket = dst >> 8 -> 256 nodes/bucket, NB=391
#define BNODES 256
#define CHUNK 8192          // edges per scatter block
#define CAP 9216            // per-bucket region capacity (mean 8184 + 11 sigma, proven r5/r6)

// ---------------- scatter: in-LDS bucket sort per chunk, coalesced dump ----------------
// packed32 = (local_dst << 24) | src   (src < 2^17, local_dst < 256)
__global__ __launch_bounds__(256) void scatter_sort_kernel(const int* __restrict__ ei,
                                                           int* __restrict__ bcur,
                                                           unsigned int* __restrict__ stage,
                                                           int E, int NB) {
    __shared__ unsigned int sbuf[CHUNK];   // 32 KB: chunk sorted by bucket
    __shared__ int lh[512];                // counts, then in-chunk cursors
    __shared__ int lofs[512];              // exclusive in-chunk offsets (sentinel at NB)
    __shared__ int lb[512];                // reserved global base per bucket
    __shared__ int tmp[256];
    int t = threadIdx.x;
    int e0 = blockIdx.x * CHUNK, e1 = min(e0 + CHUNK, E);
    int ec = e1 - e0;

    lh[t] = 0; lh[t + 256] = 0;
    __syncthreads();
    for (int e = e0 + t; e < e1; e += 256)
        atomicAdd(&lh[ei[E + e] >> BSHIFT], 1);
    __syncthreads();

    // pair-scan: 512 entries, thread t owns 2t, 2t+1 (2-way LDS alias = free)
    int c0 = lh[2 * t], c1 = lh[2 * t + 1];
    int s = c0 + c1;
    tmp[t] = s;
    __syncthreads();
    for (int off = 1; off < 256; off <<= 1) {
        int xv = (t >= off) ? tmp[t - off] : 0;
        __syncthreads();
        tmp[t] += xv;
        __syncthreads();
    }
    int ep = tmp[t] - s;                  // exclusive pair offset
    lofs[2 * t] = ep;
    lofs[2 * t + 1] = ep + c0;            // entries >= NB naturally equal ec (zero counts)
    // reserve global space per bucket (<=391 global atomics per block)
    if (2 * t < NB && c0 > 0) lb[2 * t] = 2 * t * CAP + atomicAdd(&bcur[2 * t], c0);
    if (2 * t + 1 < NB && c1 > 0) lb[2 * t + 1] = (2 * t + 1) * CAP + atomicAdd(&bcur[2 * t + 1], c1);
    lh[2 * t] = 0; lh[2 * t + 1] = 0;
    __syncthreads();

    // place edges into sbuf in bucket-sorted order
    for (int e = e0 + t; e < e1; e += 256) {
        int sN = ei[e], d = ei[E + e];
        int b = d >> BSHIFT;
        int pos = lofs[b] + atomicAdd(&lh[b], 1);
        sbuf[pos] = ((unsigned)(d & 255) << 24) | (unsigned)sN;
    }
    __syncthreads();

    // dump: i = t, t+256, ... -> consecutive lanes hit consecutive stage addrs
    int b;
    {   // binary search: largest b with lofs[b] <= t
        int lo = 0, hi = NB;
        while (lo + 1 < hi) { int mid = (lo + hi) >> 1; if (lofs[mid] <= t) lo = mid; else hi = mid; }
        b = lo;
    }
    for (int i = t; i < ec; i += 256) {
        while (i >= lofs[b + 1]) ++b;     // monotone advance (lofs[NB] == ec sentinel)
        int g = lb[b] + (i - lofs[b]);
        if (g < (b + 1) * CAP)            // capacity guard (never fires for this input)
            stage[g] = sbuf[i];
    }
}

// ---------------- per-bucket count/scan/fill in LDS + fused xp (fp16) production ----------------
__global__ __launch_bounds__(256) void bucketfill_kernel(const unsigned int* __restrict__ stage,
                                                         const int* __restrict__ bcur,
                                                         int* __restrict__ rps,
                                                         int* __restrict__ rpe,
                                                         float* __restrict__ dinv,
                                                         int* __restrict__ csr,
                                                         const float* __restrict__ x,
                                                         __half* __restrict__ xp, int n) {
    __shared__ int lcnt[BNODES];
    __shared__ int lofs[BNODES];   // scan; later reused as float dinv store
    int b = blockIdx.x;
    int base = b << BSHIFT;
    int nn = min(BNODES, n - base);
    int ecnt = min(bcur[b], CAP);
    int estart = b * CAP;
    int t = threadIdx.x;

    lcnt[t] = 0;
    __syncthreads();
    for (int e = estart + t; e < estart + ecnt; e += 256)
        atomicAdd(&lcnt[stage[e] >> 24], 1);
    __syncthreads();

    int v = (t < nn) ? lcnt[t] : 0;
    lofs[t] = v;
    __syncthreads();
    for (int off = 1; off < BNODES; off <<= 1) {
        int xv = (t >= off) ? lofs[t - off] : 0;
        __syncthreads();
        lofs[t] += xv;
        __syncthreads();
    }
    float dv = rsqrtf((float)(v + 1));   // +1 self-loop
    if (t < nn) {
        rps[base + t] = estart + lofs[t] - v;
        rpe[base + t] = estart + lofs[t];
        dinv[base + t] = dv;
    }
    __syncthreads();
    int cur0 = lofs[t] - v;              // exclusive offset -> cursor init
    __syncthreads();
    lcnt[t] = cur0;
    ((float*)lofs)[t] = dv;              // stash dinv for the xp pass
    __syncthreads();

    // ordered CSR fill (LDS atomics, sequential stage reads, bucket-local csr writes)
    for (int e = estart + t; e < estart + ecnt; e += 256) {
        unsigned int pk = stage[e];
        int d = pk >> 24;
        int pos = atomicAdd(&lcnt[d], 1);
        csr[estart + pos] = (int)(pk & 0xffffffu);
    }
    // fused pad: xp[v][j] = fp16(dinv[v]*x[v][j]) for j<18, 0 pad to 32
    for (int idx = t; idx < nn * 32; idx += 256) {
        int lv = idx >> 5, j = idx & 31;
        float val = (j < F0) ? ((float*)lofs)[lv] * x[(size_t)(base + lv) * F0 + j] : 0.f;
        xp[(size_t)(base + lv) * 32 + j] = __float2half(val);
    }
}

// ---------------- fp16 gather-aggregate ----------------
struct __align__(8) h4v { __half2 a, b; };

// out[v] = dinv[v]*(sum_e tab[src] + tab[v]) (+bias); tab fp16 rows of 32 (64 B = 1 line)
__global__ __launch_bounds__(256) void agg32h_kernel(const __half* __restrict__ tab,
                                                     const int* __restrict__ csr,
                                                     const int* __restrict__ rps,
                                                     const int* __restrict__ rpe,
                                                     const float* __restrict__ dinv,
                                                     const float* __restrict__ bias,
                                                     float* __restrict__ outp, int n) {
    int wid = (blockIdx.x * 256 + threadIdx.x) >> 6;  // node
    int lane = threadIdx.x & 63;
    if (wid >= n) return;
    int sub = lane >> 3;            // edge slot 0..7
    int q = (lane & 7) << 2;        // half-offset 0,4,..,28 (8 B per lane)
    int beg = rps[wid], end = rpe[wid];
    float4 acc = make_float4(0.f, 0.f, 0.f, 0.f);
    if (sub == 0) {                 // self-loop once
        h4v sv = *(const h4v*)&tab[(size_t)wid * 32 + q];
        float2 f0 = __half22float2(sv.a), f1 = __half22float2(sv.b);
        acc.x = f0.x; acc.y = f0.y; acc.z = f1.x; acc.w = f1.y;
    }
    int e = beg + sub;
    for (; e + 8 < end; e += 16) {  // 2 gathers in flight per lane
        int s0 = csr[e], s1 = csr[e + 8];
        h4v v0 = *(const h4v*)&tab[(size_t)s0 * 32 + q];
        h4v v1 = *(const h4v*)&tab[(size_t)s1 * 32 + q];
        float2 a0 = __half22float2(v0.a), b0 = __half22float2(v0.b);
        float2 a1 = __half22float2(v1.a), b1 = __half22float2(v1.b);
        acc.x += a0.x + a1.x; acc.y += a0.y + a1.y;
        acc.z += b0.x + b1.x; acc.w += b0.y + b1.y;
    }
    for (; e < end; e += 8) {
        int s0 = csr[e];
        h4v v0 = *(const h4v*)&tab[(size_t)s0 * 32 + q];
        float2 a0 = __half22float2(v0.a), b0 = __half22float2(v0.b);
        acc.x += a0.x; acc.y += a0.y; acc.z += b0.x; acc.w += b0.y;
    }
    for (int off = 8; off < 64; off <<= 1) {
        acc.x += __shfl_xor(acc.x, off, 64);
        acc.y += __shfl_xor(acc.y, off, 64);
        acc.z += __shfl_xor(acc.z, off, 64);
        acc.w += __shfl_xor(acc.w, off, 64);
    }
    if (sub == 0) {
        float dv = dinv[wid];
        float4 r;
        r.x = acc.x * dv; r.y = acc.y * dv; r.z = acc.z * dv; r.w = acc.w * dv;
        if (bias) { r.x += bias[q]; r.y += bias[q + 1]; r.z += bias[q + 2]; r.w += bias[q + 3]; }
        *(float4*)&outp[(size_t)wid * 32 + q] = r;
    }
}

// fused MLP: h2p[v][j] = fp16( dinv[v] * (relu(ax[v]@W1 + b1) @ W2)[j] ), 8 nodes/block
__global__ __launch_bounds__(256) void gemm_fused_kernel(const float* __restrict__ ax,
                                                         const float* __restrict__ W1,
                                                         const float* __restrict__ b1,
                                                         const float* __restrict__ W2,
                                                         const float* __restrict__ dinv,
                                                         __half* __restrict__ h2p, int n) {
    __shared__ float W1s[F0 * F1];
    __shared__ float W2s[F1 * F2];
    __shared__ float hid[8][F1];
    __shared__ float axs[8][32];
    int t = threadIdx.x;
    for (int i = t; i < F0 * F1; i += 256) W1s[i] = W1[i];
    for (int i = t; i < F1 * F2; i += 256) W2s[i] = W2[i];
    int lv = t >> 5, j = t & 31;
    int v = blockIdx.x * 8 + lv;
    if (v < n) axs[lv][j] = ax[(size_t)v * 32 + j];
    __syncthreads();
    float h0 = b1[j], h1 = b1[j + 32];
#pragma unroll
    for (int k = 0; k < F0; ++k) {
        float a = axs[lv][k];
        h0 += a * W1s[k * F1 + j];
        h1 += a * W1s[k * F1 + j + 32];
    }
    hid[lv][j] = fmaxf(h0, 0.f);
    hid[lv][j + 32] = fmaxf(h1, 0.f);
    __syncthreads();
    float acc = 0.f;
#pragma unroll
    for (int k = 0; k < F1; ++k) acc += hid[lv][k] * W2s[k * F2 + j];
    if (v < n) h2p[(size_t)v * 32 + j] = __float2half(acc * dinv[v]);
}

// ---------------- launch ----------------

extern "C" void kernel_launch(void* const* d_in, const int* in_sizes, int n_in,
                              void* d_out, int out_size, void* d_ws, size_t ws_size,
                              hipStream_t stream) {
    const float* x  = (const float*)d_in[0];
    const int*   ei = (const int*)d_in[1];
    const float* W1 = (const float*)d_in[2];
    const float* b1 = (const float*)d_in[3];
    const float* W2 = (const float*)d_in[4];
    const float* b2 = (const float*)d_in[5];
    float* out = (float*)d_out;

    int n = in_sizes[0] / F0;   // 100000
    int E = in_sizes[1] / 2;    // 3200000
    int NB = (n + BNODES - 1) >> BSHIFT;   // 391

    char* ws = (char*)d_ws;
    size_t o = 0;
    auto alloc = [&](size_t bytes) {
        char* p = ws + o;
        o = (o + bytes + 255) & ~(size_t)255;
        return p;
    };
    // Peak ~49 MB (proven-safe >= 65 MB)
    int*   rps   = (int*)alloc((size_t)n * 4);
    int*   rpe   = (int*)alloc((size_t)n * 4);
    float* dinv  = (float*)alloc((size_t)n * 4);
    int*   bcur  = (int*)alloc(512 * 4);
    int*   csr   = (int*)alloc((size_t)NB * CAP * 4);                   // 14.4 MB (gapped)
    unsigned int* stage = (unsigned int*)alloc((size_t)NB * CAP * 4);   // 14.4 MB
    float* ax    = (float*)alloc((size_t)n * 32 * 4);                   // 12.8 MB
    __half* xp   = (__half*)alloc((size_t)n * 32 * 2);                  // 6.4 MB fp16
    __half* h2p  = (__half*)stage;   // stage dead after bucketfill; reuse for fp16 h2'
    (void)ws_size; (void)n_in; (void)out_size;

    int nchunks = (E + CHUNK - 1) / CHUNK;   // 391

    hipMemsetAsync(bcur, 0, 512 * 4, stream);
    scatter_sort_kernel<<<nchunks, 256, 0, stream>>>(ei, bcur, stage, E, NB);
    bucketfill_kernel<<<NB, 256, 0, stream>>>(stage, bcur, rps, rpe, dinv, csr, x, xp, n);

    agg32h_kernel<<<(n + 3) / 4, 256, 0, stream>>>(xp, csr, rps, rpe, dinv, nullptr, ax, n);
    gemm_fused_kernel<<<(n + 7) / 8, 256, 0, stream>>>(ax, W1, b1, W2, dinv, h2p, n);
    agg32h_kernel<<<(n + 3) / 4, 256, 0, stream>>>(h2p, csr, rps, rpe, dinv, b2, out, n);
}